// Round 1
// baseline (1886.361 us; speedup 1.0000x reference)
//
#include <hip/hip_runtime.h>
#include <cstdint>
#include <cstddef>

#define SEQL 2048
#define DMODEL 1024
#define DINNER 2048
#define NSTATE 16

typedef __attribute__((ext_vector_type(4))) float f32x4;
typedef __attribute__((ext_vector_type(8))) short short8;
typedef __attribute__((ext_vector_type(4))) short short4v;
typedef unsigned short u16;

__device__ __forceinline__ float b2f(u16 u) {
  union { unsigned int i; float f; } v; v.i = ((unsigned int)u) << 16; return v.f;
}
__device__ __forceinline__ u16 f2b(float f) {
  union { float f; unsigned int i; } v; v.f = f;
  unsigned int r = v.i + 0x7FFFu + ((v.i >> 16) & 1u);
  return (u16)(r >> 16);
}

// ---- transpose + fp32->bf16 : out[c][r] = in[r][c0+c], out is (Cout x R)
__global__ __launch_bounds__(256) void k_transpose_cvt(
    const float* __restrict__ in, u16* __restrict__ out, int R, int C, int c0) {
  __shared__ float t[32][33];
  int cb = blockIdx.x * 32, rb = blockIdx.y * 32;
  int tx = threadIdx.x, ty = threadIdx.y;
#pragma unroll
  for (int i = 0; i < 32; i += 8)
    t[ty + i][tx] = in[(size_t)(rb + ty + i) * C + c0 + cb + tx];
  __syncthreads();
#pragma unroll
  for (int i = 0; i < 32; i += 8)
    out[(size_t)(cb + ty + i) * R + rb + tx] = f2b(t[tx][ty + i]);
}

// ---- LayerNorm over DMODEL, rows = B*L, bf16 in -> bf16 out
__global__ __launch_bounds__(256) void k_layernorm(
    const u16* __restrict__ xt, const float* __restrict__ w,
    const float* __restrict__ b, u16* __restrict__ xn) {
  int row = blockIdx.x;
  const u16* px = xt + (size_t)row * DMODEL;
  int i4 = threadIdx.x * 4;
  short4v sv = *(const short4v*)&px[i4];
  float v[4];
#pragma unroll
  for (int j = 0; j < 4; ++j) v[j] = b2f((u16)sv[j]);
  float s1 = v[0] + v[1] + v[2] + v[3];
  float s2 = v[0]*v[0] + v[1]*v[1] + v[2]*v[2] + v[3]*v[3];
#pragma unroll
  for (int off = 32; off > 0; off >>= 1) {
    s1 += __shfl_xor(s1, off);
    s2 += __shfl_xor(s2, off);
  }
  __shared__ float a1[4], a2[4];
  int lane = threadIdx.x & 63, wid = threadIdx.x >> 6;
  if (lane == 0) { a1[wid] = s1; a2[wid] = s2; }
  __syncthreads();
  float t1 = a1[0] + a1[1] + a1[2] + a1[3];
  float t2 = a2[0] + a2[1] + a2[2] + a2[3];
  float mu = t1 * (1.f / DMODEL);
  float rs = rsqrtf(t2 * (1.f / DMODEL) - mu * mu + 1e-5f);
  short4v ov;
#pragma unroll
  for (int j = 0; j < 4; ++j) ov[j] = (short)f2b((v[j] - mu) * rs * w[i4 + j] + b[i4 + j]);
  *(short4v*)&xn[(size_t)row * DMODEL + i4] = ov;
}

// ---- bf16 MFMA GEMM: C[M,N] = A[M,K] * BT[N,K]^T, 128x128 tile, 4 waves
// EPI: 0 = f32 store; 1 = bf16 store; 2 = f32 softplus(acc+bias[col]);
//      3 = transposed store + residual: out[(b*N+c)*SEQL+t], row=b*SEQL+t
template<int EPI>
__global__ __launch_bounds__(256) void gemm_bf16(
    const u16* __restrict__ A, const u16* __restrict__ BT,
    void* __restrict__ outp, const float* __restrict__ bias,
    const float* __restrict__ resid, int M, int N, int K) {
  __shared__ u16 As[128 * 32];
  __shared__ u16 Bs[128 * 32];
  int tid = threadIdx.x;
  int w = tid >> 6, lane = tid & 63;
  int wr = w >> 1, wc = w & 1;
  int tm = blockIdx.y * 128, tn = blockIdx.x * 128;
  int lg = lane >> 4, lr = lane & 15;
  int srow = lane >> 2;           // 0..15 within staging chunk
  int scol = (lane & 3) * 8;      // k-offset of the 16B this lane stages

  f32x4 acc[4][4] = {};

  for (int k0 = 0; k0 < K; k0 += 32) {
#pragma unroll
    for (int j = 0; j < 2; ++j) {
      int ch = w * 2 + j;  // 8 chunks of 16 rows each
      const u16* ga = A + (size_t)(tm + ch * 16 + srow) * K + k0 + scol;
      __builtin_amdgcn_global_load_lds(
          (const __attribute__((address_space(1))) void*)ga,
          (__attribute__((address_space(3))) void*)&As[ch * 512], 16, 0, 0);
      const u16* gb = BT + (size_t)(tn + ch * 16 + srow) * K + k0 + scol;
      __builtin_amdgcn_global_load_lds(
          (const __attribute__((address_space(1))) void*)gb,
          (__attribute__((address_space(3))) void*)&Bs[ch * 512], 16, 0, 0);
    }
    __syncthreads();
    short8 aF[4], bF[4];
#pragma unroll
    for (int m = 0; m < 4; ++m)
      aF[m] = *(const short8*)&As[(wr * 64 + m * 16 + lr) * 32 + lg * 8];
#pragma unroll
    for (int n = 0; n < 4; ++n)
      bF[n] = *(const short8*)&Bs[(wc * 64 + n * 16 + lr) * 32 + lg * 8];
#pragma unroll
    for (int m = 0; m < 4; ++m)
#pragma unroll
      for (int n = 0; n < 4; ++n)
        acc[m][n] = __builtin_amdgcn_mfma_f32_16x16x32_bf16(aF[m], bF[n], acc[m][n], 0, 0, 0);
    __syncthreads();
  }

#pragma unroll
  for (int m = 0; m < 4; ++m) {
    int r0 = tm + wr * 64 + m * 16 + lg * 4;
#pragma unroll
    for (int n = 0; n < 4; ++n) {
      int c = tn + wc * 64 + n * 16 + lr;
      f32x4 v = acc[m][n];
#pragma unroll
      for (int j = 0; j < 4; ++j) {
        int r = r0 + j;
        if (EPI == 0) {
          ((float*)outp)[(size_t)r * N + c] = v[j];
        } else if (EPI == 1) {
          ((u16*)outp)[(size_t)r * N + c] = f2b(v[j]);
        } else if (EPI == 2) {
          float xv = v[j] + bias[c];
          ((float*)outp)[(size_t)r * N + c] = (xv > 20.f) ? xv : log1pf(__expf(xv));
        } else {
          int bb = r >> 11, t = r & (SEQL - 1);
          size_t oi = ((size_t)(bb * N + c)) * SEQL + t;
          ((float*)outp)[oi] = v[j] + resid[oi];
        }
      }
    }
  }
}

// ---- depthwise causal conv(k=4) + bias + silu; reads xz[...,0:2048]
__global__ __launch_bounds__(256) void k_conv_silu(
    const float* __restrict__ xz, const float* __restrict__ cw,
    const float* __restrict__ cb, u16* __restrict__ xbt, float* __restrict__ uo) {
  size_t idx = (size_t)blockIdx.x * 256 + threadIdx.x;  // B*L*DINNER threads
  int d = (int)(idx & (DINNER - 1));
  int l = (int)((idx >> 11) & (SEQL - 1));
  int b = (int)(idx >> 22);
  f32x4 w = *(const f32x4*)&cw[d * 4];
  float acc = cb[d];
  size_t base = ((size_t)b * SEQL) * 4096 + d;
#pragma unroll
  for (int i = 0; i < 4; ++i) {
    int ls = l - 3 + i;
    if (ls >= 0) acc += w[i] * xz[base + (size_t)ls * 4096];
  }
  float s = acc / (1.f + __expf(-acc));
  xbt[idx] = f2b(s);
  uo[idx] = s;
}

// ---- skinny GEMM: bc[r, j<32] = sum_k xbt[r,k] * Wx[k, j]
__global__ __launch_bounds__(256) void k_bc(
    const u16* __restrict__ xbt, const float* __restrict__ Wx, float* __restrict__ bco) {
  int r = blockIdx.x * 8 + (threadIdx.x >> 5);
  int j = threadIdx.x & 31;
  const u16* a = xbt + (size_t)r * DINNER;
  const float* wp = Wx + j;
  float acc = 0.f;
  for (int k = 0; k < DINNER; k += 8) {
#pragma unroll
    for (int kk = 0; kk < 8; ++kk)
      acc += b2f(a[k + kk]) * wp[(size_t)(k + kk) * 2080];
  }
  bco[(size_t)r * 32 + j] = acc;
}

// ---- selective scan: thread = (b, d, s); 16 s-lanes reduce per y
__global__ __launch_bounds__(256) void k_scan(
    const float* __restrict__ dlt, const float* __restrict__ ui,
    const float* __restrict__ bcv, const float* __restrict__ xz,
    const float* __restrict__ A_log, const float* __restrict__ Dskip,
    u16* __restrict__ yg) {
  int blk = blockIdx.x;                    // B * DINNER/16 = 256 blocks
  int b = blk >> 7;
  int d = ((blk & 127) << 4) + (threadIdx.x >> 4);
  int s = threadIdx.x & 15;
  float Av = -__expf(A_log[d * NSTATE + s]);
  float Dsk = Dskip[d];
  float h = 0.f;
  size_t rowbase = (size_t)b * SEQL;
  for (int t = 0; t < SEQL; ++t) {
    size_t row = rowbase + t;
    float dl = dlt[row * DINNER + d];
    float uu = ui[row * DINNER + d];
    float Bv = bcv[row * 32 + s];
    float Cv = bcv[row * 32 + 16 + s];
    float dA = __expf(dl * Av);
    h = dA * h + (dl * uu) * Bv;
    float p = h * Cv;
    p += __shfl_xor(p, 1, 16);
    p += __shfl_xor(p, 2, 16);
    p += __shfl_xor(p, 4, 16);
    p += __shfl_xor(p, 8, 16);
    if (s == 0) {
      float zv = xz[row * 4096 + DINNER + d];
      float yv = (p + Dsk * uu) * (zv / (1.f + __expf(-zv)));
      yg[row * DINNER + d] = f2b(yv);
    }
  }
}

extern "C" void kernel_launch(void* const* d_in, const int* in_sizes, int n_in,
                              void* d_out, int out_size, void* d_ws, size_t ws_size,
                              hipStream_t stream) {
  (void)in_sizes; (void)n_in; (void)out_size; (void)ws_size;
  const float* x      = (const float*)d_in[0];
  const float* ln_w   = (const float*)d_in[1];
  const float* ln_b   = (const float*)d_in[2];
  const float* W_in   = (const float*)d_in[3];
  const float* conv_w = (const float*)d_in[4];
  const float* conv_b = (const float*)d_in[5];
  const float* W_x    = (const float*)d_in[6];
  const float* W_dt   = (const float*)d_in[7];
  const float* b_dt   = (const float*)d_in[8];
  const float* A_log  = (const float*)d_in[9];
  const float* Dskip  = (const float*)d_in[10];
  const float* W_out  = (const float*)d_in[11];
  float* out = (float*)d_out;

  char* ws = (char*)d_ws;
  u16*  xt    = (u16*)(ws + 0);            //  8 MB  bf16 (B,L,DMODEL)
  u16*  xn    = (u16*)(ws + 8388608);      //  8 MB  bf16 (B*L, DMODEL)
  u16*  WinT  = (u16*)(ws + 16777216);     //  8 MB  bf16 (4096,1024)
  u16*  WxT   = (u16*)(ws + 25165824);     //  8 MB  bf16 (2048,2048) cols 32..2080 of W_x, transposed
  u16*  WdtT  = (u16*)(ws + 33554432);     //  8 MB  bf16 (2048,2048)
  u16*  WoutT = (u16*)(ws + 41943040);     //  4 MB  bf16 (1024,2048)
  float* xz   = (float*)(ws + 46137344);   // 64 MB  f32 (B*L, 4096)
  u16*  xbt   = (u16*)(ws + 113246208);    // 16 MB  bf16 (B*L, DINNER)
  float* u    = (float*)(ws + 130023424);  // 32 MB  f32 (B*L, DINNER)
  float* bc   = (float*)(ws + 163577856);  // 0.5 MB f32 (B*L, 32)
  u16*  dtin  = (u16*)(ws + 164102144);    // 16 MB  bf16 (B*L, DINNER)
  float* dlt  = (float*)(ws + 180879360);  // 32 MB  f32 (B*L, DINNER)  [ends 214,433,792]
  u16*  yg    = (u16*)(ws + 0);            // 16 MB  bf16, aliases xt+xn (dead by then)

  dim3 tb(32, 8);
  // x (B, DMODEL, L) -> xt (B, L, DMODEL) bf16
  for (int b = 0; b < 2; ++b)
    k_transpose_cvt<<<dim3(SEQL / 32, DMODEL / 32), tb, 0, stream>>>(
        x + (size_t)b * DMODEL * SEQL, xt + (size_t)b * SEQL * DMODEL, DMODEL, SEQL, 0);
  // weight transposes to (N, K) bf16
  k_transpose_cvt<<<dim3(4096 / 32, 1024 / 32), tb, 0, stream>>>(W_in, WinT, 1024, 4096, 0);
  k_transpose_cvt<<<dim3(2048 / 32, 2048 / 32), tb, 0, stream>>>(W_x, WxT, 2048, 2080, 32);
  k_transpose_cvt<<<dim3(2048 / 32, 2048 / 32), tb, 0, stream>>>(W_dt, WdtT, 2048, 2048, 0);
  k_transpose_cvt<<<dim3(1024 / 32, 2048 / 32), tb, 0, stream>>>(W_out, WoutT, 2048, 1024, 0);

  k_layernorm<<<4096, 256, 0, stream>>>(xt, ln_w, ln_b, xn);

  // xz = xn @ W_in   (4096 x 4096, K=1024)
  gemm_bf16<0><<<dim3(4096 / 128, 4096 / 128), 256, 0, stream>>>(
      xn, WinT, xz, nullptr, nullptr, 4096, 4096, 1024);

  k_conv_silu<<<32768, 256, 0, stream>>>(xz, conv_w, conv_b, xbt, u);

  k_bc<<<512, 256, 0, stream>>>(xbt, W_x, bc);

  // dtin = xbt @ W_x[:,32:]  (bf16 out, 4096 x 2048, K=2048)
  gemm_bf16<1><<<dim3(2048 / 128, 4096 / 128), 256, 0, stream>>>(
      xbt, WxT, dtin, nullptr, nullptr, 4096, 2048, 2048);

  // dlt = softplus(dtin @ W_dt + b_dt)  (f32, 4096 x 2048, K=2048)
  gemm_bf16<2><<<dim3(2048 / 128, 4096 / 128), 256, 0, stream>>>(
      dtin, WdtT, dlt, b_dt, nullptr, 4096, 2048, 2048);

  k_scan<<<256, 256, 0, stream>>>(dlt, u, bc, xz, A_log, Dskip, yg);

  // out = yg @ W_out, transposed store + residual  (4096 x 1024, K=2048)
  gemm_bf16<3><<<dim3(1024 / 128, 4096 / 128), 256, 0, stream>>>(
      yg, WoutT, out, nullptr, x, 4096, 1024, 2048);
}

// Round 2
// 527.964 us; speedup vs baseline: 3.5729x; 3.5729x over previous
//
#include <hip/hip_runtime.h>
#include <cstdint>
#include <cstddef>

#define SEQL 2048
#define DMODEL 1024
#define DINNER 2048
#define NSTATE 16
#define NC 32          // scan chunks
#define TC 64          // SEQL / NC

typedef __attribute__((ext_vector_type(4))) float f32x4;
typedef __attribute__((ext_vector_type(8))) short short8;
typedef __attribute__((ext_vector_type(4))) short short4v;
typedef unsigned short u16;

__device__ __forceinline__ float b2f(u16 u) {
  union { unsigned int i; float f; } v; v.i = ((unsigned int)u) << 16; return v.f;
}
__device__ __forceinline__ u16 f2b(float f) {
  union { float f; unsigned int i; } v; v.f = f;
  unsigned int r = v.i + 0x7FFFu + ((v.i >> 16) & 1u);
  return (u16)(r >> 16);
}

// ---- transpose + fp32->bf16 : out[c][r] = in[r][c0+c], out is (Cout x R)
__global__ __launch_bounds__(256) void k_transpose_cvt(
    const float* __restrict__ in, u16* __restrict__ out, int R, int C, int c0) {
  __shared__ float t[32][33];
  int cb = blockIdx.x * 32, rb = blockIdx.y * 32;
  int tx = threadIdx.x, ty = threadIdx.y;
#pragma unroll
  for (int i = 0; i < 32; i += 8)
    t[ty + i][tx] = in[(size_t)(rb + ty + i) * C + c0 + cb + tx];
  __syncthreads();
#pragma unroll
  for (int i = 0; i < 32; i += 8)
    out[(size_t)(cb + ty + i) * R + rb + tx] = f2b(t[tx][ty + i]);
}

// ---- LayerNorm over DMODEL, rows = B*L, bf16 in -> bf16 out
__global__ __launch_bounds__(256) void k_layernorm(
    const u16* __restrict__ xt, const float* __restrict__ w,
    const float* __restrict__ b, u16* __restrict__ xn) {
  int row = blockIdx.x;
  const u16* px = xt + (size_t)row * DMODEL;
  int i4 = threadIdx.x * 4;
  short4v sv = *(const short4v*)&px[i4];
  float v[4];
#pragma unroll
  for (int j = 0; j < 4; ++j) v[j] = b2f((u16)sv[j]);
  float s1 = v[0] + v[1] + v[2] + v[3];
  float s2 = v[0]*v[0] + v[1]*v[1] + v[2]*v[2] + v[3]*v[3];
#pragma unroll
  for (int off = 32; off > 0; off >>= 1) {
    s1 += __shfl_xor(s1, off);
    s2 += __shfl_xor(s2, off);
  }
  __shared__ float a1[4], a2[4];
  int lane = threadIdx.x & 63, wid = threadIdx.x >> 6;
  if (lane == 0) { a1[wid] = s1; a2[wid] = s2; }
  __syncthreads();
  float t1 = a1[0] + a1[1] + a1[2] + a1[3];
  float t2 = a2[0] + a2[1] + a2[2] + a2[3];
  float mu = t1 * (1.f / DMODEL);
  float rs = rsqrtf(t2 * (1.f / DMODEL) - mu * mu + 1e-5f);
  short4v ov;
#pragma unroll
  for (int j = 0; j < 4; ++j) ov[j] = (short)f2b((v[j] - mu) * rs * w[i4 + j] + b[i4 + j]);
  *(short4v*)&xn[(size_t)row * DMODEL + i4] = ov;
}

// ---- bf16 MFMA GEMM: C[M,N] = A[M,K] * BT[N,K]^T, 128x128 tile, 4 waves
// EPI: 0 = f32 store; 1 = bf16 store; 2 = f32 softplus(acc+bias[col]);
//      3 = transposed store + residual: out[(b*N+c)*SEQL+t], row=b*SEQL+t
template<int EPI>
__global__ __launch_bounds__(256) void gemm_bf16(
    const u16* __restrict__ A, const u16* __restrict__ BT,
    void* __restrict__ outp, const float* __restrict__ bias,
    const float* __restrict__ resid, int M, int N, int K) {
  __shared__ u16 As[128 * 32];
  __shared__ u16 Bs[128 * 32];
  int tid = threadIdx.x;
  int w = tid >> 6, lane = tid & 63;
  int wr = w >> 1, wc = w & 1;
  int tm = blockIdx.y * 128, tn = blockIdx.x * 128;
  int lg = lane >> 4, lr = lane & 15;
  int srow = lane >> 2;           // 0..15 within staging chunk
  int scol = (lane & 3) * 8;      // k-offset of the 16B this lane stages

  f32x4 acc[4][4] = {};

  for (int k0 = 0; k0 < K; k0 += 32) {
#pragma unroll
    for (int j = 0; j < 2; ++j) {
      int ch = w * 2 + j;  // 8 chunks of 16 rows each
      const u16* ga = A + (size_t)(tm + ch * 16 + srow) * K + k0 + scol;
      __builtin_amdgcn_global_load_lds(
          (const __attribute__((address_space(1))) void*)ga,
          (__attribute__((address_space(3))) void*)&As[ch * 512], 16, 0, 0);
      const u16* gb = BT + (size_t)(tn + ch * 16 + srow) * K + k0 + scol;
      __builtin_amdgcn_global_load_lds(
          (const __attribute__((address_space(1))) void*)gb,
          (__attribute__((address_space(3))) void*)&Bs[ch * 512], 16, 0, 0);
    }
    __syncthreads();
    short8 aF[4], bF[4];
#pragma unroll
    for (int m = 0; m < 4; ++m)
      aF[m] = *(const short8*)&As[(wr * 64 + m * 16 + lr) * 32 + lg * 8];
#pragma unroll
    for (int n = 0; n < 4; ++n)
      bF[n] = *(const short8*)&Bs[(wc * 64 + n * 16 + lr) * 32 + lg * 8];
#pragma unroll
    for (int m = 0; m < 4; ++m)
#pragma unroll
      for (int n = 0; n < 4; ++n)
        acc[m][n] = __builtin_amdgcn_mfma_f32_16x16x32_bf16(aF[m], bF[n], acc[m][n], 0, 0, 0);
    __syncthreads();
  }

#pragma unroll
  for (int m = 0; m < 4; ++m) {
    int r0 = tm + wr * 64 + m * 16 + lg * 4;
#pragma unroll
    for (int n = 0; n < 4; ++n) {
      int c = tn + wc * 64 + n * 16 + lr;
      f32x4 v = acc[m][n];
#pragma unroll
      for (int j = 0; j < 4; ++j) {
        int r = r0 + j;
        if (EPI == 0) {
          ((float*)outp)[(size_t)r * N + c] = v[j];
        } else if (EPI == 1) {
          ((u16*)outp)[(size_t)r * N + c] = f2b(v[j]);
        } else if (EPI == 2) {
          float xv = v[j] + bias[c];
          ((float*)outp)[(size_t)r * N + c] = (xv > 20.f) ? xv : log1pf(__expf(xv));
        } else {
          int bb = r >> 11, t = r & (SEQL - 1);
          size_t oi = ((size_t)(bb * N + c)) * SEQL + t;
          ((float*)outp)[oi] = v[j] + resid[oi];
        }
      }
    }
  }
}

// ---- depthwise causal conv(k=4) + bias + silu; reads xz[...,0:2048]
__global__ __launch_bounds__(256) void k_conv_silu(
    const float* __restrict__ xz, const float* __restrict__ cw,
    const float* __restrict__ cb, u16* __restrict__ xbt, float* __restrict__ uo) {
  size_t idx = (size_t)blockIdx.x * 256 + threadIdx.x;  // B*L*DINNER threads
  int d = (int)(idx & (DINNER - 1));
  int l = (int)((idx >> 11) & (SEQL - 1));
  int b = (int)(idx >> 22);
  f32x4 w = *(const f32x4*)&cw[d * 4];
  float acc = cb[d];
  size_t base = ((size_t)b * SEQL) * 4096 + d;
#pragma unroll
  for (int i = 0; i < 4; ++i) {
    int ls = l - 3 + i;
    if (ls >= 0) acc += w[i] * xz[base + (size_t)ls * 4096];
  }
  float s = acc / (1.f + __expf(-acc));
  xbt[idx] = f2b(s);
  uo[idx] = s;
}

// ---- skinny GEMM: bc[r, j<32] = sum_k xbt[r,k] * Wx[k, j]
__global__ __launch_bounds__(256) void k_bc(
    const u16* __restrict__ xbt, const float* __restrict__ Wx, float* __restrict__ bco) {
  int r = blockIdx.x * 8 + (threadIdx.x >> 5);
  int j = threadIdx.x & 31;
  const u16* a = xbt + (size_t)r * DINNER;
  const float* wp = Wx + j;
  float acc = 0.f;
  for (int k = 0; k < DINNER; k += 8) {
#pragma unroll
    for (int kk = 0; kk < 8; ++kk)
      acc += b2f(a[k + kk]) * wp[(size_t)(k + kk) * 2080];
  }
  bco[(size_t)r * 32 + j] = acc;
}

// ==== chunked selective scan ====
// Phase 1: per (b, d, chunk) compute transfer P = prod dA, Q = chunk-local h
// (from h=0). One thread owns all 16 states. Store layout [b][c][d][s].
__global__ __launch_bounds__(256) void k_scan_p1(
    const float* __restrict__ dlt, const float* __restrict__ ui,
    const float* __restrict__ bcv, const float* __restrict__ A_log,
    float* __restrict__ Pc, float* __restrict__ Qc) {
  int d = blockIdx.x * 256 + threadIdx.x;   // 0..2047, lane-fast -> coalesced
  int c = blockIdx.y;
  int b = blockIdx.z;
  float Av[16];
#pragma unroll
  for (int sv = 0; sv < 4; ++sv) {
    f32x4 al = *(const f32x4*)&A_log[d * 16 + sv * 4];
#pragma unroll
    for (int j = 0; j < 4; ++j) Av[sv * 4 + j] = -__expf(al[j]);
  }
  float P[16], Q[16];
#pragma unroll
  for (int s = 0; s < 16; ++s) { P[s] = 1.f; Q[s] = 0.f; }
  size_t row0 = (size_t)b * SEQL + (size_t)c * TC;
  for (int t = 0; t < TC; ++t) {
    size_t row = row0 + t;
    float dl = dlt[row * DINNER + d];
    float uu = ui[row * DINNER + d];
    float bco = dl * uu;
    const f32x4* Bp = (const f32x4*)&bcv[row * 32];
#pragma unroll
    for (int sv = 0; sv < 4; ++sv) {
      f32x4 Bv = Bp[sv];
#pragma unroll
      for (int j = 0; j < 4; ++j) {
        int s = sv * 4 + j;
        float dA = __expf(dl * Av[s]);
        P[s] *= dA;
        Q[s] = dA * Q[s] + bco * Bv[j];
      }
    }
  }
  size_t base = (((size_t)b * NC + c) * DINNER + d) * 16;
#pragma unroll
  for (int sv = 0; sv < 4; ++sv) {
    f32x4 pv, qv;
#pragma unroll
    for (int j = 0; j < 4; ++j) { pv[j] = P[sv * 4 + j]; qv[j] = Q[sv * 4 + j]; }
    *(f32x4*)&Pc[base + sv * 4] = pv;
    *(f32x4*)&Qc[base + sv * 4] = qv;
  }
}

// Phase 2: per (b,d,s) compose chunk transfers -> h_start per chunk.
__global__ __launch_bounds__(256) void k_scan_p2(
    const float* __restrict__ Pc, const float* __restrict__ Qc,
    float* __restrict__ Hs) {
  size_t gid = (size_t)blockIdx.x * 256 + threadIdx.x;  // 65536 threads
  // gid = ((b*DINNER)+d)*16 + s ; consecutive gid -> consecutive (d,s) addr
  size_t bds = gid & ((size_t)DINNER * 16 - 1);
  int b = (int)(gid >> 15);
  float h = 0.f;
  size_t cstride = (size_t)DINNER * 16;
  size_t base = (size_t)b * NC * cstride + bds;
  for (int c = 0; c < NC; ++c) {
    size_t idx = base + (size_t)c * cstride;
    Hs[idx] = h;
    h = Pc[idx] * h + Qc[idx];
  }
}

// Phase 3: replay each chunk from h_start; y = sum_s h*C in-thread; fuse
// D-skip + silu(z) gate; bf16 store.
__global__ __launch_bounds__(256) void k_scan_p3(
    const float* __restrict__ dlt, const float* __restrict__ ui,
    const float* __restrict__ bcv, const float* __restrict__ xz,
    const float* __restrict__ A_log, const float* __restrict__ Dskip,
    const float* __restrict__ Hs, u16* __restrict__ yg) {
  int d = blockIdx.x * 256 + threadIdx.x;
  int c = blockIdx.y;
  int b = blockIdx.z;
  float Av[16];
#pragma unroll
  for (int sv = 0; sv < 4; ++sv) {
    f32x4 al = *(const f32x4*)&A_log[d * 16 + sv * 4];
#pragma unroll
    for (int j = 0; j < 4; ++j) Av[sv * 4 + j] = -__expf(al[j]);
  }
  float h[16];
  size_t hb = (((size_t)b * NC + c) * DINNER + d) * 16;
#pragma unroll
  for (int sv = 0; sv < 4; ++sv) {
    f32x4 hv = *(const f32x4*)&Hs[hb + sv * 4];
#pragma unroll
    for (int j = 0; j < 4; ++j) h[sv * 4 + j] = hv[j];
  }
  float Dsk = Dskip[d];
  size_t row0 = (size_t)b * SEQL + (size_t)c * TC;
  for (int t = 0; t < TC; ++t) {
    size_t row = row0 + t;
    float dl = dlt[row * DINNER + d];
    float uu = ui[row * DINNER + d];
    float bco = dl * uu;
    const f32x4* BCp = (const f32x4*)&bcv[row * 32];
    float y = 0.f;
#pragma unroll
    for (int sv = 0; sv < 4; ++sv) {
      f32x4 Bv = BCp[sv];
      f32x4 Cv = BCp[4 + sv];
#pragma unroll
      for (int j = 0; j < 4; ++j) {
        int s = sv * 4 + j;
        float dA = __expf(dl * Av[s]);
        h[s] = dA * h[s] + bco * Bv[j];
        y += h[s] * Cv[j];
      }
    }
    float zv = xz[row * 4096 + DINNER + d];
    float yv = (y + Dsk * uu) * (zv / (1.f + __expf(-zv)));
    yg[row * DINNER + d] = f2b(yv);
  }
}

extern "C" void kernel_launch(void* const* d_in, const int* in_sizes, int n_in,
                              void* d_out, int out_size, void* d_ws, size_t ws_size,
                              hipStream_t stream) {
  (void)in_sizes; (void)n_in; (void)out_size; (void)ws_size;
  const float* x      = (const float*)d_in[0];
  const float* ln_w   = (const float*)d_in[1];
  const float* ln_b   = (const float*)d_in[2];
  const float* W_in   = (const float*)d_in[3];
  const float* conv_w = (const float*)d_in[4];
  const float* conv_b = (const float*)d_in[5];
  const float* W_x    = (const float*)d_in[6];
  const float* W_dt   = (const float*)d_in[7];
  const float* b_dt   = (const float*)d_in[8];
  const float* A_log  = (const float*)d_in[9];
  const float* Dskip  = (const float*)d_in[10];
  const float* W_out  = (const float*)d_in[11];
  float* out = (float*)d_out;

  char* ws = (char*)d_ws;
  u16*  xt    = (u16*)(ws + 0);            //  8 MB  bf16 (B,L,DMODEL)
  u16*  xn    = (u16*)(ws + 8388608);      //  8 MB  bf16 (B*L, DMODEL)
  u16*  WinT  = (u16*)(ws + 16777216);     //  8 MB  bf16 (4096,1024)
  u16*  WxT   = (u16*)(ws + 25165824);     //  8 MB  bf16 (2048,2048), dead after gemm<1>
  u16*  WdtT  = (u16*)(ws + 33554432);     //  8 MB  bf16 (2048,2048), dead after gemm<2>
  u16*  WoutT = (u16*)(ws + 41943040);     //  4 MB  bf16 (1024,2048)
  float* xz   = (float*)(ws + 46137344);   // 64 MB  f32 (B*L, 4096)
  u16*  xbt   = (u16*)(ws + 113246208);    // 16 MB  bf16 (B*L, DINNER)
  float* u    = (float*)(ws + 130023424);  // 32 MB  f32 (B*L, DINNER)
  float* bc   = (float*)(ws + 163577856);  // 0.5 MB f32 (B*L, 32)
  u16*  dtin  = (u16*)(ws + 164102144);    // 16 MB  bf16, dead after gemm<2>
  float* dlt  = (float*)(ws + 180879360);  // 32 MB  f32 (B*L, DINNER)
  u16*  yg    = (u16*)(ws + 0);            // 16 MB  bf16, aliases xt+xn (dead)
  // scan scratch reuses dead regions:
  float* Pc   = (float*)(ws + 25165824);   // 8 MB, aliases WxT
  float* Qc   = (float*)(ws + 33554432);   // 8 MB, aliases WdtT
  float* Hs   = (float*)(ws + 164102144);  // 8 MB, aliases dtin

  dim3 tb(32, 8);
  // x (B, DMODEL, L) -> xt (B, L, DMODEL) bf16
  for (int b = 0; b < 2; ++b)
    k_transpose_cvt<<<dim3(SEQL / 32, DMODEL / 32), tb, 0, stream>>>(
        x + (size_t)b * DMODEL * SEQL, xt + (size_t)b * SEQL * DMODEL, DMODEL, SEQL, 0);
  // weight transposes to (N, K) bf16
  k_transpose_cvt<<<dim3(4096 / 32, 1024 / 32), tb, 0, stream>>>(W_in, WinT, 1024, 4096, 0);
  k_transpose_cvt<<<dim3(2048 / 32, 2048 / 32), tb, 0, stream>>>(W_x, WxT, 2048, 2080, 32);
  k_transpose_cvt<<<dim3(2048 / 32, 2048 / 32), tb, 0, stream>>>(W_dt, WdtT, 2048, 2048, 0);
  k_transpose_cvt<<<dim3(1024 / 32, 2048 / 32), tb, 0, stream>>>(W_out, WoutT, 2048, 1024, 0);

  k_layernorm<<<4096, 256, 0, stream>>>(xt, ln_w, ln_b, xn);

  // xz = xn @ W_in   (4096 x 4096, K=1024)
  gemm_bf16<0><<<dim3(4096 / 128, 4096 / 128), 256, 0, stream>>>(
      xn, WinT, xz, nullptr, nullptr, 4096, 4096, 1024);

  k_conv_silu<<<32768, 256, 0, stream>>>(xz, conv_w, conv_b, xbt, u);

  k_bc<<<512, 256, 0, stream>>>(xbt, W_x, bc);

  // dtin = xbt @ W_x[:,32:]  (bf16 out, 4096 x 2048, K=2048)
  gemm_bf16<1><<<dim3(2048 / 128, 4096 / 128), 256, 0, stream>>>(
      xbt, WxT, dtin, nullptr, nullptr, 4096, 2048, 2048);

  // dlt = softplus(dtin @ W_dt + b_dt)  (f32, 4096 x 2048, K=2048)
  gemm_bf16<2><<<dim3(2048 / 128, 4096 / 128), 256, 0, stream>>>(
      dtin, WdtT, dlt, b_dt, nullptr, 4096, 2048, 2048);

  // chunked scan
  k_scan_p1<<<dim3(DINNER / 256, NC, 2), 256, 0, stream>>>(
      dlt, u, bc, A_log, Pc, Qc);
  k_scan_p2<<<256, 256, 0, stream>>>(Pc, Qc, Hs);
  k_scan_p3<<<dim3(DINNER / 256, NC, 2), 256, 0, stream>>>(
      dlt, u, bc, xz, A_log, Dskip, Hs, yg);

  // out = yg @ W_out, transposed store + residual  (4096 x 1024, K=2048)
  gemm_bf16<3><<<dim3(1024 / 128, 4096 / 128), 256, 0, stream>>>(
      yg, WoutT, out, nullptr, x, 4096, 1024, 2048);
}

// Round 3
// 403.786 us; speedup vs baseline: 4.6717x; 1.3075x over previous
//
#include <hip/hip_runtime.h>
#include <cstdint>
#include <cstddef>

#define SEQL 2048
#define DMODEL 1024
#define DINNER 2048
#define NSTATE 16
#define NC 32          // scan chunks
#define TC 64          // SEQL / NC
#define KS 16          // k_bc split-K chunks
#define KCH 128        // DINNER / KS

typedef __attribute__((ext_vector_type(4))) float f32x4;
typedef __attribute__((ext_vector_type(8))) short short8;
typedef __attribute__((ext_vector_type(4))) short short4v;
typedef unsigned short u16;

__device__ __forceinline__ float b2f(u16 u) {
  union { unsigned int i; float f; } v; v.i = ((unsigned int)u) << 16; return v.f;
}
__device__ __forceinline__ u16 f2b(float f) {
  union { float f; unsigned int i; } v; v.f = f;
  unsigned int r = v.i + 0x7FFFu + ((v.i >> 16) & 1u);
  return (u16)(r >> 16);
}

// ---- transpose + fp32->bf16 : out[c][r] = in[r][c0+c], out is (Cout x R)
__global__ __launch_bounds__(256) void k_transpose_cvt(
    const float* __restrict__ in, u16* __restrict__ out, int R, int C, int c0) {
  __shared__ float t[32][33];
  int cb = blockIdx.x * 32, rb = blockIdx.y * 32;
  int tx = threadIdx.x, ty = threadIdx.y;
#pragma unroll
  for (int i = 0; i < 32; i += 8)
    t[ty + i][tx] = in[(size_t)(rb + ty + i) * C + c0 + cb + tx];
  __syncthreads();
#pragma unroll
  for (int i = 0; i < 32; i += 8)
    out[(size_t)(cb + ty + i) * R + rb + tx] = f2b(t[tx][ty + i]);
}

// ---- LayerNorm over DMODEL, rows = B*L, bf16 in -> bf16 out
__global__ __launch_bounds__(256) void k_layernorm(
    const u16* __restrict__ xt, const float* __restrict__ w,
    const float* __restrict__ b, u16* __restrict__ xn) {
  int row = blockIdx.x;
  const u16* px = xt + (size_t)row * DMODEL;
  int i4 = threadIdx.x * 4;
  short4v sv = *(const short4v*)&px[i4];
  float v[4];
#pragma unroll
  for (int j = 0; j < 4; ++j) v[j] = b2f((u16)sv[j]);
  float s1 = v[0] + v[1] + v[2] + v[3];
  float s2 = v[0]*v[0] + v[1]*v[1] + v[2]*v[2] + v[3]*v[3];
#pragma unroll
  for (int off = 32; off > 0; off >>= 1) {
    s1 += __shfl_xor(s1, off);
    s2 += __shfl_xor(s2, off);
  }
  __shared__ float a1[4], a2[4];
  int lane = threadIdx.x & 63, wid = threadIdx.x >> 6;
  if (lane == 0) { a1[wid] = s1; a2[wid] = s2; }
  __syncthreads();
  float t1 = a1[0] + a1[1] + a1[2] + a1[3];
  float t2 = a2[0] + a2[1] + a2[2] + a2[3];
  float mu = t1 * (1.f / DMODEL);
  float rs = rsqrtf(t2 * (1.f / DMODEL) - mu * mu + 1e-5f);
  short4v ov;
#pragma unroll
  for (int j = 0; j < 4; ++j) ov[j] = (short)f2b((v[j] - mu) * rs * w[i4 + j] + b[i4 + j]);
  *(short4v*)&xn[(size_t)row * DMODEL + i4] = ov;
}

// ---- bf16 MFMA GEMM: C[M,N] = A[M,K] * BT[N,K]^T, 128x128 tile, 4 waves
// EPI: 0 = f32 store; 1 = bf16 store; 2 = f32 softplus(acc+bias[col]);
//      3 = transposed store + residual: out[(b*N+c)*SEQL+t], row=b*SEQL+t
template<int EPI>
__global__ __launch_bounds__(256) void gemm_bf16(
    const u16* __restrict__ A, const u16* __restrict__ BT,
    void* __restrict__ outp, const float* __restrict__ bias,
    const float* __restrict__ resid, int M, int N, int K) {
  __shared__ u16 As[128 * 32];
  __shared__ u16 Bs[128 * 32];
  int tid = threadIdx.x;
  int w = tid >> 6, lane = tid & 63;
  int wr = w >> 1, wc = w & 1;
  int tm = blockIdx.y * 128, tn = blockIdx.x * 128;
  int lg = lane >> 4, lr = lane & 15;
  int srow = lane >> 2;           // 0..15 within staging chunk
  int scol = (lane & 3) * 8;      // k-offset of the 16B this lane stages

  f32x4 acc[4][4] = {};

  for (int k0 = 0; k0 < K; k0 += 32) {
#pragma unroll
    for (int j = 0; j < 2; ++j) {
      int ch = w * 2 + j;  // 8 chunks of 16 rows each
      const u16* ga = A + (size_t)(tm + ch * 16 + srow) * K + k0 + scol;
      __builtin_amdgcn_global_load_lds(
          (const __attribute__((address_space(1))) void*)ga,
          (__attribute__((address_space(3))) void*)&As[ch * 512], 16, 0, 0);
      const u16* gb = BT + (size_t)(tn + ch * 16 + srow) * K + k0 + scol;
      __builtin_amdgcn_global_load_lds(
          (const __attribute__((address_space(1))) void*)gb,
          (__attribute__((address_space(3))) void*)&Bs[ch * 512], 16, 0, 0);
    }
    __syncthreads();
    short8 aF[4], bF[4];
#pragma unroll
    for (int m = 0; m < 4; ++m)
      aF[m] = *(const short8*)&As[(wr * 64 + m * 16 + lr) * 32 + lg * 8];
#pragma unroll
    for (int n = 0; n < 4; ++n)
      bF[n] = *(const short8*)&Bs[(wc * 64 + n * 16 + lr) * 32 + lg * 8];
#pragma unroll
    for (int m = 0; m < 4; ++m)
#pragma unroll
      for (int n = 0; n < 4; ++n)
        acc[m][n] = __builtin_amdgcn_mfma_f32_16x16x32_bf16(aF[m], bF[n], acc[m][n], 0, 0, 0);
    __syncthreads();
  }

#pragma unroll
  for (int m = 0; m < 4; ++m) {
    int r0 = tm + wr * 64 + m * 16 + lg * 4;
#pragma unroll
    for (int n = 0; n < 4; ++n) {
      int c = tn + wc * 64 + n * 16 + lr;
      f32x4 v = acc[m][n];
#pragma unroll
      for (int j = 0; j < 4; ++j) {
        int r = r0 + j;
        if (EPI == 0) {
          ((float*)outp)[(size_t)r * N + c] = v[j];
        } else if (EPI == 1) {
          ((u16*)outp)[(size_t)r * N + c] = f2b(v[j]);
        } else if (EPI == 2) {
          float xv = v[j] + bias[c];
          ((float*)outp)[(size_t)r * N + c] = (xv > 20.f) ? xv : log1pf(__expf(xv));
        } else {
          int bb = r >> 11, t = r & (SEQL - 1);
          size_t oi = ((size_t)(bb * N + c)) * SEQL + t;
          ((float*)outp)[oi] = v[j] + resid[oi];
        }
      }
    }
  }
}

// ---- depthwise causal conv(k=4) + bias + silu; reads xz[...,0:2048]
__global__ __launch_bounds__(256) void k_conv_silu(
    const float* __restrict__ xz, const float* __restrict__ cw,
    const float* __restrict__ cb, u16* __restrict__ xbt, float* __restrict__ uo) {
  size_t idx = (size_t)blockIdx.x * 256 + threadIdx.x;  // B*L*DINNER threads
  int d = (int)(idx & (DINNER - 1));
  int l = (int)((idx >> 11) & (SEQL - 1));
  int b = (int)(idx >> 22);
  f32x4 w = *(const f32x4*)&cw[d * 4];
  float acc = cb[d];
  size_t base = ((size_t)b * SEQL) * 4096 + d;
#pragma unroll
  for (int i = 0; i < 4; ++i) {
    int ls = l - 3 + i;
    if (ls >= 0) acc += w[i] * xz[base + (size_t)ls * 4096];
  }
  float s = acc / (1.f + __expf(-acc));
  xbt[idx] = f2b(s);
  uo[idx] = s;
}

// ---- split-K MFMA skinny GEMM: bcp[ks][r][j] = sum_{k in chunk} xbt[r,k]*WxBCT[j,k]
__global__ __launch_bounds__(256) void k_bc_mfma(
    const u16* __restrict__ xbt, const u16* __restrict__ WxBCT,
    float* __restrict__ bcp) {
  __shared__ u16 As[128 * 32];
  int tid = threadIdx.x;
  int w = tid >> 6, lane = tid & 63;
  int tm = blockIdx.x * 128;
  int k0 = blockIdx.y * KCH;
  int lg = lane >> 4, lr = lane & 15;
  int srow = lane >> 2, scol = (lane & 3) * 8;

  f32x4 acc[2][2] = {};

  for (int kk = k0; kk < k0 + KCH; kk += 32) {
#pragma unroll
    for (int j = 0; j < 2; ++j) {
      int ch = w * 2 + j;
      const u16* ga = xbt + (size_t)(tm + ch * 16 + srow) * DINNER + kk + scol;
      __builtin_amdgcn_global_load_lds(
          (const __attribute__((address_space(1))) void*)ga,
          (__attribute__((address_space(3))) void*)&As[ch * 512], 16, 0, 0);
    }
    __syncthreads();
    short8 aF[2], bF[2];
#pragma unroll
    for (int m = 0; m < 2; ++m)
      aF[m] = *(const short8*)&As[(w * 32 + m * 16 + lr) * 32 + lg * 8];
#pragma unroll
    for (int n = 0; n < 2; ++n)
      bF[n] = *(const short8*)&WxBCT[(size_t)(n * 16 + lr) * DINNER + kk + lg * 8];
#pragma unroll
    for (int m = 0; m < 2; ++m)
#pragma unroll
      for (int n = 0; n < 2; ++n)
        acc[m][n] = __builtin_amdgcn_mfma_f32_16x16x32_bf16(aF[m], bF[n], acc[m][n], 0, 0, 0);
    __syncthreads();
  }

  float* outp = bcp + (size_t)blockIdx.y * (4096 * 32);
#pragma unroll
  for (int m = 0; m < 2; ++m) {
    int r0 = tm + w * 32 + m * 16 + lg * 4;
#pragma unroll
    for (int n = 0; n < 2; ++n) {
      int c = n * 16 + lr;
      f32x4 v = acc[m][n];
#pragma unroll
      for (int j = 0; j < 4; ++j)
        outp[(size_t)(r0 + j) * 32 + c] = v[j];
    }
  }
}

// ---- reduce split-K partials: bc[i] = sum_ks bcp[ks][i]
__global__ __launch_bounds__(256) void k_bc_red(
    const float* __restrict__ bcp, float* __restrict__ bc) {
  size_t i = (size_t)blockIdx.x * 256 + threadIdx.x;  // 131072
  float s = 0.f;
#pragma unroll
  for (int ks = 0; ks < KS; ++ks)
    s += bcp[(size_t)ks * (4096 * 32) + i];
  bc[i] = s;
}

// ==== chunked selective scan ====
// Phase 1: per (b, d, chunk) compute transfer P = prod dA, Q = chunk-local h
__global__ __launch_bounds__(256) void k_scan_p1(
    const float* __restrict__ dlt, const float* __restrict__ ui,
    const float* __restrict__ bcv, const float* __restrict__ A_log,
    float* __restrict__ Pc, float* __restrict__ Qc) {
  int d = blockIdx.x * 256 + threadIdx.x;
  int c = blockIdx.y;
  int b = blockIdx.z;
  float Av[16];
#pragma unroll
  for (int sv = 0; sv < 4; ++sv) {
    f32x4 al = *(const f32x4*)&A_log[d * 16 + sv * 4];
#pragma unroll
    for (int j = 0; j < 4; ++j) Av[sv * 4 + j] = -__expf(al[j]);
  }
  float P[16], Q[16];
#pragma unroll
  for (int s = 0; s < 16; ++s) { P[s] = 1.f; Q[s] = 0.f; }
  size_t row0 = (size_t)b * SEQL + (size_t)c * TC;
  for (int t = 0; t < TC; ++t) {
    size_t row = row0 + t;
    float dl = dlt[row * DINNER + d];
    float uu = ui[row * DINNER + d];
    float bco = dl * uu;
    const f32x4* Bp = (const f32x4*)&bcv[row * 32];
#pragma unroll
    for (int sv = 0; sv < 4; ++sv) {
      f32x4 Bv = Bp[sv];
#pragma unroll
      for (int j = 0; j < 4; ++j) {
        int s = sv * 4 + j;
        float dA = __expf(dl * Av[s]);
        P[s] *= dA;
        Q[s] = dA * Q[s] + bco * Bv[j];
      }
    }
  }
  size_t base = (((size_t)b * NC + c) * DINNER + d) * 16;
#pragma unroll
  for (int sv = 0; sv < 4; ++sv) {
    f32x4 pv, qv;
#pragma unroll
    for (int j = 0; j < 4; ++j) { pv[j] = P[sv * 4 + j]; qv[j] = Q[sv * 4 + j]; }
    *(f32x4*)&Pc[base + sv * 4] = pv;
    *(f32x4*)&Qc[base + sv * 4] = qv;
  }
}

// Phase 2: per (b,d,s) compose chunk transfers -> h_start per chunk.
__global__ __launch_bounds__(256) void k_scan_p2(
    const float* __restrict__ Pc, const float* __restrict__ Qc,
    float* __restrict__ Hs) {
  size_t gid = (size_t)blockIdx.x * 256 + threadIdx.x;
  size_t bds = gid & ((size_t)DINNER * 16 - 1);
  int b = (int)(gid >> 15);
  float h = 0.f;
  size_t cstride = (size_t)DINNER * 16;
  size_t base = (size_t)b * NC * cstride + bds;
  for (int c = 0; c < NC; ++c) {
    size_t idx = base + (size_t)c * cstride;
    Hs[idx] = h;
    h = Pc[idx] * h + Qc[idx];
  }
}

// Phase 3: replay each chunk from h_start; y in-thread; D-skip + silu(z) gate.
__global__ __launch_bounds__(256) void k_scan_p3(
    const float* __restrict__ dlt, const float* __restrict__ ui,
    const float* __restrict__ bcv, const float* __restrict__ xz,
    const float* __restrict__ A_log, const float* __restrict__ Dskip,
    const float* __restrict__ Hs, u16* __restrict__ yg) {
  int d = blockIdx.x * 256 + threadIdx.x;
  int c = blockIdx.y;
  int b = blockIdx.z;
  float Av[16];
#pragma unroll
  for (int sv = 0; sv < 4; ++sv) {
    f32x4 al = *(const f32x4*)&A_log[d * 16 + sv * 4];
#pragma unroll
    for (int j = 0; j < 4; ++j) Av[sv * 4 + j] = -__expf(al[j]);
  }
  float h[16];
  size_t hb = (((size_t)b * NC + c) * DINNER + d) * 16;
#pragma unroll
  for (int sv = 0; sv < 4; ++sv) {
    f32x4 hv = *(const f32x4*)&Hs[hb + sv * 4];
#pragma unroll
    for (int j = 0; j < 4; ++j) h[sv * 4 + j] = hv[j];
  }
  float Dsk = Dskip[d];
  size_t row0 = (size_t)b * SEQL + (size_t)c * TC;
  for (int t = 0; t < TC; ++t) {
    size_t row = row0 + t;
    float dl = dlt[row * DINNER + d];
    float uu = ui[row * DINNER + d];
    float bco = dl * uu;
    const f32x4* BCp = (const f32x4*)&bcv[row * 32];
    float y = 0.f;
#pragma unroll
    for (int sv = 0; sv < 4; ++sv) {
      f32x4 Bv = BCp[sv];
      f32x4 Cv = BCp[4 + sv];
#pragma unroll
      for (int j = 0; j < 4; ++j) {
        int s = sv * 4 + j;
        float dA = __expf(dl * Av[s]);
        h[s] = dA * h[s] + bco * Bv[j];
        y += h[s] * Cv[j];
      }
    }
    float zv = xz[row * 4096 + DINNER + d];
    float yv = (y + Dsk * uu) * (zv / (1.f + __expf(-zv)));
    yg[row * DINNER + d] = f2b(yv);
  }
}

extern "C" void kernel_launch(void* const* d_in, const int* in_sizes, int n_in,
                              void* d_out, int out_size, void* d_ws, size_t ws_size,
                              hipStream_t stream) {
  (void)in_sizes; (void)n_in; (void)out_size; (void)ws_size;
  const float* x      = (const float*)d_in[0];
  const float* ln_w   = (const float*)d_in[1];
  const float* ln_b   = (const float*)d_in[2];
  const float* W_in   = (const float*)d_in[3];
  const float* conv_w = (const float*)d_in[4];
  const float* conv_b = (const float*)d_in[5];
  const float* W_x    = (const float*)d_in[6];
  const float* W_dt   = (const float*)d_in[7];
  const float* b_dt   = (const float*)d_in[8];
  const float* A_log  = (const float*)d_in[9];
  const float* Dskip  = (const float*)d_in[10];
  const float* W_out  = (const float*)d_in[11];
  float* out = (float*)d_out;

  char* ws = (char*)d_ws;
  u16*  xt    = (u16*)(ws + 0);            //  8 MB  bf16 (B,L,DMODEL)
  u16*  xn    = (u16*)(ws + 8388608);      //  8 MB  bf16 (B*L, DMODEL)
  u16*  WinT  = (u16*)(ws + 16777216);     //  8 MB  bf16 (4096,1024)
  u16*  WxT   = (u16*)(ws + 25165824);     //  8 MB  bf16 (2048,2048), dead after gemm<1>
  u16*  WdtT  = (u16*)(ws + 33554432);     //  8 MB  bf16 (2048,2048), dead after gemm<2>
  u16*  WoutT = (u16*)(ws + 41943040);     //  4 MB  bf16 (1024,2048)
  float* xz   = (float*)(ws + 46137344);   // 64 MB  f32 (B*L, 4096)
  u16*  xbt   = (u16*)(ws + 113246208);    // 16 MB  bf16 (B*L, DINNER)
  float* u    = (float*)(ws + 130023424);  // 32 MB  f32 (B*L, DINNER)
  float* bc   = (float*)(ws + 163577856);  // 0.5 MB f32 (B*L, 32)
  u16*  dtin  = (u16*)(ws + 164102144);    // 16 MB  bf16, live gemm<1>..gemm<2>
  float* dlt  = (float*)(ws + 180879360);  // 32 MB  f32 (B*L, DINNER)
  u16*  yg    = (u16*)(ws + 0);            // 16 MB  bf16, aliases xt+xn (dead)
  // scan scratch reuses dead regions:
  float* Pc   = (float*)(ws + 25165824);   // 8 MB, aliases WxT
  float* Qc   = (float*)(ws + 33554432);   // 8 MB, aliases WdtT
  float* Hs   = (float*)(ws + 164102144);  // 8 MB, aliases dtin (dead after gemm<2>)
  // k_bc scratch:
  float* bcp  = (float*)(ws + 0);          // 8 MB partials, aliases xt/xn (dead by then; yg written later)
  u16*  WxBCT = (u16*)(ws + 164102144);    // 128 KB, aliases dtin (dead until gemm<1>)

  dim3 tb(32, 8);
  // x (B, DMODEL, L) -> xt (B, L, DMODEL) bf16
  for (int b = 0; b < 2; ++b)
    k_transpose_cvt<<<dim3(SEQL / 32, DMODEL / 32), tb, 0, stream>>>(
        x + (size_t)b * DMODEL * SEQL, xt + (size_t)b * SEQL * DMODEL, DMODEL, SEQL, 0);
  // weight transposes to (N, K) bf16
  k_transpose_cvt<<<dim3(4096 / 32, 1024 / 32), tb, 0, stream>>>(W_in, WinT, 1024, 4096, 0);
  k_transpose_cvt<<<dim3(2048 / 32, 2048 / 32), tb, 0, stream>>>(W_x, WxT, 2048, 2080, 32);
  k_transpose_cvt<<<dim3(32 / 32, 2048 / 32), tb, 0, stream>>>(W_x, WxBCT, 2048, 2080, 0);
  k_transpose_cvt<<<dim3(2048 / 32, 2048 / 32), tb, 0, stream>>>(W_dt, WdtT, 2048, 2048, 0);
  k_transpose_cvt<<<dim3(1024 / 32, 2048 / 32), tb, 0, stream>>>(W_out, WoutT, 2048, 1024, 0);

  k_layernorm<<<4096, 256, 0, stream>>>(xt, ln_w, ln_b, xn);

  // xz = xn @ W_in   (4096 x 4096, K=1024)
  gemm_bf16<0><<<dim3(4096 / 128, 4096 / 128), 256, 0, stream>>>(
      xn, WinT, xz, nullptr, nullptr, 4096, 4096, 1024);

  k_conv_silu<<<32768, 256, 0, stream>>>(xz, conv_w, conv_b, xbt, u);

  // bc = xbt @ W_x[:, :32]  via split-K MFMA + reduce
  k_bc_mfma<<<dim3(4096 / 128, KS), 256, 0, stream>>>(xbt, WxBCT, bcp);
  k_bc_red<<<131072 / 256, 256, 0, stream>>>(bcp, bc);

  // dtin = xbt @ W_x[:,32:]  (bf16 out, 4096 x 2048, K=2048)
  gemm_bf16<1><<<dim3(2048 / 128, 4096 / 128), 256, 0, stream>>>(
      xbt, WxT, dtin, nullptr, nullptr, 4096, 2048, 2048);

  // dlt = softplus(dtin @ W_dt + b_dt)  (f32, 4096 x 2048, K=2048)
  gemm_bf16<2><<<dim3(2048 / 128, 4096 / 128), 256, 0, stream>>>(
      dtin, WdtT, dlt, b_dt, nullptr, 4096, 2048, 2048);

  // chunked scan
  k_scan_p1<<<dim3(DINNER / 256, NC, 2), 256, 0, stream>>>(
      dlt, u, bc, A_log, Pc, Qc);
  k_scan_p2<<<256, 256, 0, stream>>>(Pc, Qc, Hs);
  k_scan_p3<<<dim3(DINNER / 256, NC, 2), 256, 0, stream>>>(
      dlt, u, bc, xz, A_log, Dskip, Hs, yg);

  // out = yg @ W_out, transposed store + residual  (4096 x 1024, K=2048)
  gemm_bf16<3><<<dim3(1024 / 128, 4096 / 128), 256, 0, stream>>>(
      yg, WoutT, out, nullptr, x, 4096, 1024, 2048);
}

// Round 5
// 361.692 us; speedup vs baseline: 5.2154x; 1.1164x over previous
//
#include <hip/hip_runtime.h>
#include <cstdint>
#include <cstddef>

#define SEQL 2048
#define DMODEL 1024
#define DINNER 2048
#define NSTATE 16
#define NC 32          // scan chunks
#define TC 64          // SEQL / NC
#define KS 16          // k_bc split-K chunks
#define KCH 128        // DINNER / KS

typedef __attribute__((ext_vector_type(4))) float f32x4;
typedef __attribute__((ext_vector_type(8))) short short8;
typedef __attribute__((ext_vector_type(4))) short short4v;
typedef unsigned short u16;

__device__ __forceinline__ float b2f(u16 u) {
  union { unsigned int i; float f; } v; v.i = ((unsigned int)u) << 16; return v.f;
}
__device__ __forceinline__ u16 f2b(float f) {
  union { float f; unsigned int i; } v; v.f = f;
  unsigned int r = v.i + 0x7FFFu + ((v.i >> 16) & 1u);
  return (u16)(r >> 16);
}

// ---- transpose + fp32->bf16 : out[c][r] = in[r][c0+c], out is (Cout x R)
__global__ __launch_bounds__(256) void k_transpose_cvt(
    const float* __restrict__ in, u16* __restrict__ out, int R, int C, int c0) {
  __shared__ float t[32][33];
  int cb = blockIdx.x * 32, rb = blockIdx.y * 32;
  int tx = threadIdx.x, ty = threadIdx.y;
#pragma unroll
  for (int i = 0; i < 32; i += 8)
    t[ty + i][tx] = in[(size_t)(rb + ty + i) * C + c0 + cb + tx];
  __syncthreads();
#pragma unroll
  for (int i = 0; i < 32; i += 8)
    out[(size_t)(cb + ty + i) * R + rb + tx] = f2b(t[tx][ty + i]);
}

// ---- LayerNorm over DMODEL, rows = B*L, bf16 in -> bf16 out
__global__ __launch_bounds__(256) void k_layernorm(
    const u16* __restrict__ xt, const float* __restrict__ w,
    const float* __restrict__ b, u16* __restrict__ xn) {
  int row = blockIdx.x;
  const u16* px = xt + (size_t)row * DMODEL;
  int i4 = threadIdx.x * 4;
  short4v sv = *(const short4v*)&px[i4];
  float v[4];
#pragma unroll
  for (int j = 0; j < 4; ++j) v[j] = b2f((u16)sv[j]);
  float s1 = v[0] + v[1] + v[2] + v[3];
  float s2 = v[0]*v[0] + v[1]*v[1] + v[2]*v[2] + v[3]*v[3];
#pragma unroll
  for (int off = 32; off > 0; off >>= 1) {
    s1 += __shfl_xor(s1, off);
    s2 += __shfl_xor(s2, off);
  }
  __shared__ float a1[4], a2[4];
  int lane = threadIdx.x & 63, wid = threadIdx.x >> 6;
  if (lane == 0) { a1[wid] = s1; a2[wid] = s2; }
  __syncthreads();
  float t1 = a1[0] + a1[1] + a1[2] + a1[3];
  float t2 = a2[0] + a2[1] + a2[2] + a2[3];
  float mu = t1 * (1.f / DMODEL);
  float rs = rsqrtf(t2 * (1.f / DMODEL) - mu * mu + 1e-5f);
  short4v ov;
#pragma unroll
  for (int j = 0; j < 4; ++j) ov[j] = (short)f2b((v[j] - mu) * rs * w[i4 + j] + b[i4 + j]);
  *(short4v*)&xn[(size_t)row * DMODEL + i4] = ov;
}

// ==================== 8-phase 256xBN MFMA GEMM ====================
// C[M,N] = A[M,K] * BT[N,K]^T. 512 threads = 8 waves (2 M x 4 N).
// BM=256, BK=64, double-buffered swizzled LDS, counted vmcnt (T3+T4),
// XOR swizzle (T2), setprio around MFMA (T5), XCD-aware block swizzle (T1).
// EPI: 0 = f32 store; 1 = bf16 store; 2 = f32 softplus(acc + bias[col]).
template<int BN, int EPI>
__global__ __launch_bounds__(512) void gemm8p(
    const u16* __restrict__ A, const u16* __restrict__ BT,
    void* __restrict__ outp, const float* __restrict__ bias,
    int M, int N, int K) {
  constexpr int NF  = BN / 64;     // n-frags per wave
  constexpr int NFH = NF / 2;      // n-frags per quadrant
  constexpr int WN  = BN / 4;      // per-wave col span
  constexpr int G   = 16 * NFH;    // B-half row granule
  constexpr int SB  = BN / 128;    // stage instrs per B-half (A-half: 2)
  constexpr int LDSTILE = 64 * (256 + BN);
  __shared__ u16 lds[2 * LDSTILE];

  const int tid = threadIdx.x;
  const int w = tid >> 6, lane = tid & 63;
  const int wm = w >> 2, wn = w & 3;
  const int lg = lane >> 4, lr = lane & 15;
  const int wbase = tid & ~63;

  const int gx = N / BN;
  const int cpx = gridDim.x >> 3;
  const int wg = ((int)blockIdx.x & 7) * cpx + ((int)blockIdx.x >> 3);
  const int tm = (wg / gx) * 256;
  const int tn = (wg % gx) * BN;
  const int NT = K >> 6;

  const u16* Ab = A + (size_t)tm * K;
  const u16* Bb = BT + (size_t)tn * K;

  // stage A-half h of tile tc (rows with bit6==h in each 128-row wm-panel)
  auto stageA = [&](int tc, int h) {
    int tcl = tc < NT ? tc : NT - 1;
    const u16* g0 = Ab + (size_t)tcl * 64;
    u16* l0 = lds + (tc & 1) * LDSTILE;
#pragma unroll
    for (int j = 0; j < 2; ++j) {
      int t8 = j * 512 + tid;
      int r8 = t8 >> 3;                                // 0..127 in half
      int pr = (r8 & 63) + ((r8 >> 6) << 7) + h * 64;  // physical tile row
      int sk = ((((t8 & 7) << 4) ^ ((pr & 7) << 4)) >> 1);
      int r8b = (j * 512 + wbase) >> 3;
      int prb = (r8b & 63) + ((r8b >> 6) << 7) + h * 64;
      __builtin_amdgcn_global_load_lds(
          (const __attribute__((address_space(1))) void*)(g0 + (size_t)pr * K + sk),
          (__attribute__((address_space(3))) void*)(l0 + prb * 64), 16, 0, 0);
    }
  };
  // stage B-half h of tile tc (rows with granule-G parity h in each 2G panel)
  auto stageB = [&](int tc, int h) {
    int tcl = tc < NT ? tc : NT - 1;
    const u16* g0 = Bb + (size_t)tcl * 64;
    u16* l0 = lds + (tc & 1) * LDSTILE + 256 * 64;
#pragma unroll
    for (int j = 0; j < SB; ++j) {
      int t8 = j * 512 + tid;
      int r8 = t8 >> 3;                                  // 0..BN/2-1 in half
      int pr = (r8 % G) + (r8 / G) * 2 * G + h * G;      // physical B row
      int sk = ((((t8 & 7) << 4) ^ ((pr & 7) << 4)) >> 1);
      int r8b = (j * 512 + wbase) >> 3;
      int prb = (r8b % G) + (r8b / G) * 2 * G + h * G;
      __builtin_amdgcn_global_load_lds(
          (const __attribute__((address_space(1))) void*)(g0 + (size_t)pr * K + sk),
          (__attribute__((address_space(3))) void*)(l0 + prb * 64), 16, 0, 0);
    }
  };
  auto fragA = [&](const u16* base, int mf, int kk) -> short8 {
    int r = wm * 128 + mf * 16 + lr;
    int cb = (kk * 64 + lg * 16) ^ ((r & 7) << 4);
    return *(const short8*)((const char*)base + r * 128 + cb);
  };
  auto fragB = [&](const u16* base, int nf, int kk) -> short8 {
    int r = wn * WN + nf * 16 + lr;
    int cb = (kk * 64 + lg * 16) ^ ((r & 7) << 4);
    return *(const short8*)((const char*)base + r * 128 + cb);
  };
  auto vmw = [&]() {  // keep exactly next-2-halves (2+SB instrs) in flight
    if constexpr (SB == 2) asm volatile("s_waitcnt vmcnt(4)" ::: "memory");
    else                   asm volatile("s_waitcnt vmcnt(3)" ::: "memory");
  };

  f32x4 acc[8][NF] = {};
  short8 aF[4][2], bF0[NFH][2], bF1[NFH][2];

  // prologue: tile0 fully + first two halves of tile1
  stageA(0, 0); stageB(0, 0); stageB(0, 1); stageA(0, 1);
  stageA(1, 0); stageB(1, 0);
  vmw();
  __builtin_amdgcn_s_barrier();

  for (int t = 0; t < NT; ++t) {
    const u16* Ac = lds + (t & 1) * LDSTILE;
    const u16* Bc = Ac + 256 * 64;
    // ---- P1: read A-h0 + B-h0, MFMA Q(0,0); stage B1(t+1)
#pragma unroll
    for (int mf = 0; mf < 4; ++mf) { aF[mf][0] = fragA(Ac, mf, 0); aF[mf][1] = fragA(Ac, mf, 1); }
#pragma unroll
    for (int nf = 0; nf < NFH; ++nf) { bF0[nf][0] = fragB(Bc, nf, 0); bF0[nf][1] = fragB(Bc, nf, 1); }
    stageB(t + 1, 1);
    __builtin_amdgcn_s_barrier();
    asm volatile("s_waitcnt lgkmcnt(0)" ::: "memory");
    __builtin_amdgcn_s_setprio(1);
#pragma unroll
    for (int mf = 0; mf < 4; ++mf)
#pragma unroll
      for (int nf = 0; nf < NFH; ++nf) {
        acc[mf][nf] = __builtin_amdgcn_mfma_f32_16x16x32_bf16(aF[mf][0], bF0[nf][0], acc[mf][nf], 0, 0, 0);
        acc[mf][nf] = __builtin_amdgcn_mfma_f32_16x16x32_bf16(aF[mf][1], bF0[nf][1], acc[mf][nf], 0, 0, 0);
      }
    __builtin_amdgcn_s_setprio(0);
    __builtin_amdgcn_s_barrier();
    // ---- P2: read B-h1, MFMA Q(0,1); stage A1(t+1)
#pragma unroll
    for (int nf = 0; nf < NFH; ++nf) { bF1[nf][0] = fragB(Bc, NFH + nf, 0); bF1[nf][1] = fragB(Bc, NFH + nf, 1); }
    stageA(t + 1, 1);
    __builtin_amdgcn_s_barrier();
    asm volatile("s_waitcnt lgkmcnt(0)" ::: "memory");
    __builtin_amdgcn_s_setprio(1);
#pragma unroll
    for (int mf = 0; mf < 4; ++mf)
#pragma unroll
      for (int nf = 0; nf < NFH; ++nf) {
        acc[mf][NFH + nf] = __builtin_amdgcn_mfma_f32_16x16x32_bf16(aF[mf][0], bF1[nf][0], acc[mf][NFH + nf], 0, 0, 0);
        acc[mf][NFH + nf] = __builtin_amdgcn_mfma_f32_16x16x32_bf16(aF[mf][1], bF1[nf][1], acc[mf][NFH + nf], 0, 0, 0);
      }
    __builtin_amdgcn_s_setprio(0);
    __builtin_amdgcn_s_barrier();
    // ---- P3: read A-h1, MFMA Q(1,0); stage A0(t+2)
#pragma unroll
    for (int mf = 0; mf < 4; ++mf) { aF[mf][0] = fragA(Ac, 4 + mf, 0); aF[mf][1] = fragA(Ac, 4 + mf, 1); }
    stageA(t + 2, 0);
    __builtin_amdgcn_s_barrier();
    asm volatile("s_waitcnt lgkmcnt(0)" ::: "memory");
    __builtin_amdgcn_s_setprio(1);
#pragma unroll
    for (int mf = 0; mf < 4; ++mf)
#pragma unroll
      for (int nf = 0; nf < NFH; ++nf) {
        acc[4 + mf][nf] = __builtin_amdgcn_mfma_f32_16x16x32_bf16(aF[mf][0], bF0[nf][0], acc[4 + mf][nf], 0, 0, 0);
        acc[4 + mf][nf] = __builtin_amdgcn_mfma_f32_16x16x32_bf16(aF[mf][1], bF0[nf][1], acc[4 + mf][nf], 0, 0, 0);
      }
    __builtin_amdgcn_s_setprio(0);
    __builtin_amdgcn_s_barrier();
    // ---- P4: MFMA Q(1,1); stage B0(t+2); counted vmcnt
    stageB(t + 2, 0);
    __builtin_amdgcn_s_barrier();
    asm volatile("s_waitcnt lgkmcnt(0)" ::: "memory");
    __builtin_amdgcn_s_setprio(1);
#pragma unroll
    for (int mf = 0; mf < 4; ++mf)
#pragma unroll
      for (int nf = 0; nf < NFH; ++nf) {
        acc[4 + mf][NFH + nf] = __builtin_amdgcn_mfma_f32_16x16x32_bf16(aF[mf][0], bF1[nf][0], acc[4 + mf][NFH + nf], 0, 0, 0);
        acc[4 + mf][NFH + nf] = __builtin_amdgcn_mfma_f32_16x16x32_bf16(aF[mf][1], bF1[nf][1], acc[4 + mf][NFH + nf], 0, 0, 0);
      }
    __builtin_amdgcn_s_setprio(0);
    vmw();
    __builtin_amdgcn_s_barrier();
  }

  // epilogue
#pragma unroll
  for (int mf = 0; mf < 8; ++mf) {
    int r0 = tm + wm * 128 + mf * 16 + lg * 4;
#pragma unroll
    for (int nf = 0; nf < NF; ++nf) {
      int c = tn + wn * WN + nf * 16 + lr;
      f32x4 v = acc[mf][nf];
#pragma unroll
      for (int j = 0; j < 4; ++j) {
        int r = r0 + j;
        if constexpr (EPI == 1) {
          ((u16*)outp)[(size_t)r * N + c] = f2b(v[j]);
        } else if constexpr (EPI == 2) {
          float xv = v[j] + bias[c];
          ((float*)outp)[(size_t)r * N + c] = (xv > 20.f) ? xv : log1pf(__expf(xv));
        } else {
          ((float*)outp)[(size_t)r * N + c] = v[j];
        }
      }
    }
  }
}

// ---- old-style 128x128 MFMA GEMM, kept for EPI 3 (transposed store + residual)
template<int EPI>
__global__ __launch_bounds__(256) void gemm_bf16(
    const u16* __restrict__ A, const u16* __restrict__ BT,
    void* __restrict__ outp, const float* __restrict__ bias,
    const float* __restrict__ resid, int M, int N, int K) {
  __shared__ u16 As[128 * 32];
  __shared__ u16 Bs[128 * 32];
  int tid = threadIdx.x;
  int w = tid >> 6, lane = tid & 63;
  int wr = w >> 1, wc = w & 1;
  int tm = blockIdx.y * 128, tn = blockIdx.x * 128;
  int lg = lane >> 4, lr = lane & 15;
  int srow = lane >> 2;
  int scol = (lane & 3) * 8;

  f32x4 acc[4][4] = {};

  for (int k0 = 0; k0 < K; k0 += 32) {
#pragma unroll
    for (int j = 0; j < 2; ++j) {
      int ch = w * 2 + j;
      const u16* ga = A + (size_t)(tm + ch * 16 + srow) * K + k0 + scol;
      __builtin_amdgcn_global_load_lds(
          (const __attribute__((address_space(1))) void*)ga,
          (__attribute__((address_space(3))) void*)&As[ch * 512], 16, 0, 0);
      const u16* gb = BT + (size_t)(tn + ch * 16 + srow) * K + k0 + scol;
      __builtin_amdgcn_global_load_lds(
          (const __attribute__((address_space(1))) void*)gb,
          (__attribute__((address_space(3))) void*)&Bs[ch * 512], 16, 0, 0);
    }
    __syncthreads();
    short8 aF[4], bF[4];
#pragma unroll
    for (int m = 0; m < 4; ++m)
      aF[m] = *(const short8*)&As[(wr * 64 + m * 16 + lr) * 32 + lg * 8];
#pragma unroll
    for (int n = 0; n < 4; ++n)
      bF[n] = *(const short8*)&Bs[(wc * 64 + n * 16 + lr) * 32 + lg * 8];
#pragma unroll
    for (int m = 0; m < 4; ++m)
#pragma unroll
      for (int n = 0; n < 4; ++n)
        acc[m][n] = __builtin_amdgcn_mfma_f32_16x16x32_bf16(aF[m], bF[n], acc[m][n], 0, 0, 0);
    __syncthreads();
  }

#pragma unroll
  for (int m = 0; m < 4; ++m) {
    int r0 = tm + wr * 64 + m * 16 + lg * 4;
#pragma unroll
    for (int n = 0; n < 4; ++n) {
      int c = tn + wc * 64 + n * 16 + lr;
      f32x4 v = acc[m][n];
#pragma unroll
      for (int j = 0; j < 4; ++j) {
        int r = r0 + j;
        if (EPI == 0) {
          ((float*)outp)[(size_t)r * N + c] = v[j];
        } else if (EPI == 1) {
          ((u16*)outp)[(size_t)r * N + c] = f2b(v[j]);
        } else if (EPI == 2) {
          float xv = v[j] + bias[c];
          ((float*)outp)[(size_t)r * N + c] = (xv > 20.f) ? xv : log1pf(__expf(xv));
        } else {
          int bb = r >> 11, t = r & (SEQL - 1);
          size_t oi = ((size_t)(bb * N + c)) * SEQL + t;
          ((float*)outp)[oi] = v[j] + resid[oi];
        }
      }
    }
  }
}

// ---- depthwise causal conv(k=4) + bias + silu; reads bf16 xz[...,0:2048]
__global__ __launch_bounds__(256) void k_conv_silu(
    const u16* __restrict__ xz, const float* __restrict__ cw,
    const float* __restrict__ cb, u16* __restrict__ xbt) {
  size_t idx = (size_t)blockIdx.x * 256 + threadIdx.x;  // B*L*DINNER threads
  int d = (int)(idx & (DINNER - 1));
  int l = (int)((idx >> 11) & (SEQL - 1));
  int b = (int)(idx >> 22);
  f32x4 w = *(const f32x4*)&cw[d * 4];
  float acc = cb[d];
  size_t base = ((size_t)b * SEQL) * 4096 + d;
#pragma unroll
  for (int i = 0; i < 4; ++i) {
    int ls = l - 3 + i;
    if (ls >= 0) acc += w[i] * b2f(xz[base + (size_t)ls * 4096]);
  }
  float s = acc / (1.f + __expf(-acc));
  xbt[idx] = f2b(s);
}

// ---- split-K MFMA skinny GEMM: bcp[ks][r][j] = sum_{k in chunk} xbt[r,k]*WxBCT[j,k]
__global__ __launch_bounds__(256) void k_bc_mfma(
    const u16* __restrict__ xbt, const u16* __restrict__ WxBCT,
    float* __restrict__ bcp) {
  __shared__ u16 As[128 * 32];
  int tid = threadIdx.x;
  int w = tid >> 6, lane = tid & 63;
  int tm = blockIdx.x * 128;
  int k0 = blockIdx.y * KCH;
  int lg = lane >> 4, lr = lane & 15;
  int srow = lane >> 2, scol = (lane & 3) * 8;

  f32x4 acc[2][2] = {};

  for (int kk = k0; kk < k0 + KCH; kk += 32) {
#pragma unroll
    for (int j = 0; j < 2; ++j) {
      int ch = w * 2 + j;
      const u16* ga = xbt + (size_t)(tm + ch * 16 + srow) * DINNER + kk + scol;
      __builtin_amdgcn_global_load_lds(
          (const __attribute__((address_space(1))) void*)ga,
          (__attribute__((address_space(3))) void*)&As[ch * 512], 16, 0, 0);
    }
    __syncthreads();
    short8 aF[2], bF[2];
#pragma unroll
    for (int m = 0; m < 2; ++m)
      aF[m] = *(const short8*)&As[(w * 32 + m * 16 + lr) * 32 + lg * 8];
#pragma unroll
    for (int n = 0; n < 2; ++n)
      bF[n] = *(const short8*)&WxBCT[(size_t)(n * 16 + lr) * DINNER + kk + lg * 8];
#pragma unroll
    for (int m = 0; m < 2; ++m)
#pragma unroll
      for (int n = 0; n < 2; ++n)
        acc[m][n] = __builtin_amdgcn_mfma_f32_16x16x32_bf16(aF[m], bF[n], acc[m][n], 0, 0, 0);
    __syncthreads();
  }

  float* outp = bcp + (size_t)blockIdx.y * (4096 * 32);
#pragma unroll
  for (int m = 0; m < 2; ++m) {
    int r0 = tm + w * 32 + m * 16 + lg * 4;
#pragma unroll
    for (int n = 0; n < 2; ++n) {
      int c = n * 16 + lr;
      f32x4 v = acc[m][n];
#pragma unroll
      for (int j = 0; j < 4; ++j)
        outp[(size_t)(r0 + j) * 32 + c] = v[j];
    }
  }
}

// ---- reduce split-K partials
__global__ __launch_bounds__(256) void k_bc_red(
    const float* __restrict__ bcp, float* __restrict__ bc) {
  size_t i = (size_t)blockIdx.x * 256 + threadIdx.x;
  float s = 0.f;
#pragma unroll
  for (int ks = 0; ks < KS; ++ks)
    s += bcp[(size_t)ks * (4096 * 32) + i];
  bc[i] = s;
}

// ==== chunked selective scan ====
__global__ __launch_bounds__(256) void k_scan_p1(
    const float* __restrict__ dlt, const u16* __restrict__ ub,
    const float* __restrict__ bcv, const float* __restrict__ A_log,
    float* __restrict__ Pc, float* __restrict__ Qc) {
  int d = blockIdx.x * 256 + threadIdx.x;
  int c = blockIdx.y;
  int b = blockIdx.z;
  float Av[16];
#pragma unroll
  for (int sv = 0; sv < 4; ++sv) {
    f32x4 al = *(const f32x4*)&A_log[d * 16 + sv * 4];
#pragma unroll
    for (int j = 0; j < 4; ++j) Av[sv * 4 + j] = -__expf(al[j]);
  }
  float P[16], Q[16];
#pragma unroll
  for (int s = 0; s < 16; ++s) { P[s] = 1.f; Q[s] = 0.f; }
  size_t row0 = (size_t)b * SEQL + (size_t)c * TC;
  for (int t = 0; t < TC; ++t) {
    size_t row = row0 + t;
    float dl = dlt[row * DINNER + d];
    float uu = b2f(ub[row * DINNER + d]);
    float bco = dl * uu;
    const f32x4* Bp = (const f32x4*)&bcv[row * 32];
#pragma unroll
    for (int sv = 0; sv < 4; ++sv) {
      f32x4 Bv = Bp[sv];
#pragma unroll
      for (int j = 0; j < 4; ++j) {
        int s = sv * 4 + j;
        float dA = __expf(dl * Av[s]);
        P[s] *= dA;
        Q[s] = dA * Q[s] + bco * Bv[j];
      }
    }
  }
  size_t base = (((size_t)b * NC + c) * DINNER + d) * 16;
#pragma unroll
  for (int sv = 0; sv < 4; ++sv) {
    f32x4 pv, qv;
#pragma unroll
    for (int j = 0; j < 4; ++j) { pv[j] = P[sv * 4 + j]; qv[j] = Q[sv * 4 + j]; }
    *(f32x4*)&Pc[base + sv * 4] = pv;
    *(f32x4*)&Qc[base + sv * 4] = qv;
  }
}

__global__ __launch_bounds__(256) void k_scan_p2(
    const float* __restrict__ Pc, const float* __restrict__ Qc,
    float* __restrict__ Hs) {
  size_t gid = (size_t)blockIdx.x * 256 + threadIdx.x;
  size_t bds = gid & ((size_t)DINNER * 16 - 1);
  int b = (int)(gid >> 15);
  float h = 0.f;
  size_t cstride = (size_t)DINNER * 16;
  size_t base = (size_t)b * NC * cstride + bds;
  for (int c = 0; c < NC; ++c) {
    size_t idx = base + (size_t)c * cstride;
    Hs[idx] = h;
    h = Pc[idx] * h + Qc[idx];
  }
}

__global__ __launch_bounds__(256) void k_scan_p3(
    const float* __restrict__ dlt, const u16* __restrict__ ub,
    const float* __restrict__ bcv, const u16* __restrict__ xz,
    const float* __restrict__ A_log, const float* __restrict__ Dskip,
    const float* __restrict__ Hs, u16* __restrict__ yg) {
  int d = blockIdx.x * 256 + threadIdx.x;
  int c = blockIdx.y;
  int b = blockIdx.z;
  float Av[16];
#pragma unroll
  for (int sv = 0; sv < 4; ++sv) {
    f32x4 al = *(const f32x4*)&A_log[d * 16 + sv * 4];
#pragma unroll
    for (int j = 0; j < 4; ++j) Av[sv * 4 + j] = -__expf(al[j]);
  }
  float h[16];
  size_t hb = (((size_t)b * NC + c) * DINNER + d) * 16;
#pragma unroll
  for (int sv = 0; sv < 4; ++sv) {
    f32x4 hv = *(const f32x4*)&Hs[hb + sv * 4];
#pragma unroll
    for (int j = 0; j < 4; ++j) h[sv * 4 + j] = hv[j];
  }
  float Dsk = Dskip[d];
  size_t row0 = (size_t)b * SEQL + (size_t)c * TC;
  for (int t = 0; t < TC; ++t) {
    size_t row = row0 + t;
    float dl = dlt[row * DINNER + d];
    float uu = b2f(ub[row * DINNER + d]);
    float bco = dl * uu;
    const f32x4* BCp = (const f32x4*)&bcv[row * 32];
    float y = 0.f;
#pragma unroll
    for (int sv = 0; sv < 4; ++sv) {
      f32x4 Bv = BCp[sv];
      f32x4 Cv = BCp[4 + sv];
#pragma unroll
      for (int j = 0; j < 4; ++j) {
        int s = sv * 4 + j;
        float dA = __expf(dl * Av[s]);
        h[s] = dA * h[s] + bco * Bv[j];
        y += h[s] * Cv[j];
      }
    }
    float zv = b2f(xz[row * 4096 + DINNER + d]);
    float yv = (y + Dsk * uu) * (zv / (1.f + __expf(-zv)));
    yg[row * DINNER + d] = f2b(yv);
  }
}

extern "C" void kernel_launch(void* const* d_in, const int* in_sizes, int n_in,
                              void* d_out, int out_size, void* d_ws, size_t ws_size,
                              hipStream_t stream) {
  (void)in_sizes; (void)n_in; (void)out_size; (void)ws_size;
  const float* x      = (const float*)d_in[0];
  const float* ln_w   = (const float*)d_in[1];
  const float* ln_b   = (const float*)d_in[2];
  const float* W_in   = (const float*)d_in[3];
  const float* conv_w = (const float*)d_in[4];
  const float* conv_b = (const float*)d_in[5];
  const float* W_x    = (const float*)d_in[6];
  const float* W_dt   = (const float*)d_in[7];
  const float* b_dt   = (const float*)d_in[8];
  const float* A_log  = (const float*)d_in[9];
  const float* Dskip  = (const float*)d_in[10];
  const float* W_out  = (const float*)d_in[11];
  float* out = (float*)d_out;

  char* ws = (char*)d_ws;
  const size_t MB = 1048576;
  u16*  xt    = (u16*)(ws + 0 * MB);     //  8 MB bf16 (B,L,DMODEL); dead after LN
  u16*  xn    = (u16*)(ws + 8 * MB);     //  8 MB bf16; dead after gemm<0>
  u16*  WinT  = (u16*)(ws + 16 * MB);    //  8 MB bf16 (4096,1024)
  u16*  WxT   = (u16*)(ws + 24 * MB);    //  8 MB bf16 (2048,2048)
  u16*  WdtT  = (u16*)(ws + 32 * MB);    //  8 MB bf16 (2048,2048)
  u16*  WoutT = (u16*)(ws + 40 * MB);    //  4 MB bf16 (1024,2048)
  u16*  xz    = (u16*)(ws + 44 * MB);    // 32 MB bf16 (B*L, 4096)
  u16*  xbt   = (u16*)(ws + 76 * MB);    // 16 MB bf16 (B*L, DINNER)
  float* bc   = (float*)(ws + 92 * MB);  // 0.5 MB f32 (B*L, 32)
  u16*  dtin  = (u16*)(ws + 93 * MB);    // 16 MB bf16
  float* dlt  = (float*)(ws + 109 * MB); // 32 MB f32 (B*L, DINNER)
  float* Pc   = (float*)(ws + 141 * MB); //  8 MB
  float* Qc   = (float*)(ws + 149 * MB); //  8 MB
  float* Hs   = (float*)(ws + 157 * MB); //  8 MB
  float* bcp  = (float*)(ws + 165 * MB); //  8 MB split-K partials
  u16*  WxBCT = (u16*)(ws + 173 * MB);   // 128 KB bf16 (32,2048)
  u16*  yg    = (u16*)(ws + 0 * MB);     // 16 MB bf16, aliases xt+xn (dead)

  dim3 tb(32, 8);
  for (int b = 0; b < 2; ++b)
    k_transpose_cvt<<<dim3(SEQL / 32, DMODEL / 32), tb, 0, stream>>>(
        x + (size_t)b * DMODEL * SEQL, xt + (size_t)b * SEQL * DMODEL, DMODEL, SEQL, 0);
  k_transpose_cvt<<<dim3(4096 / 32, 1024 / 32), tb, 0, stream>>>(W_in, WinT, 1024, 4096, 0);
  k_transpose_cvt<<<dim3(2048 / 32, 2048 / 32), tb, 0, stream>>>(W_x, WxT, 2048, 2080, 32);
  k_transpose_cvt<<<dim3(1, 2048 / 32), tb, 0, stream>>>(W_x, WxBCT, 2048, 2080, 0);
  k_transpose_cvt<<<dim3(2048 / 32, 2048 / 32), tb, 0, stream>>>(W_dt, WdtT, 2048, 2048, 0);
  k_transpose_cvt<<<dim3(1024 / 32, 2048 / 32), tb, 0, stream>>>(W_out, WoutT, 2048, 1024, 0);

  k_layernorm<<<4096, 256, 0, stream>>>(xt, ln_w, ln_b, xn);

  // xz = xn @ W_in   (4096 x 4096, K=1024), bf16 out
  gemm8p<128, 1><<<512, 512, 0, stream>>>(xn, WinT, xz, nullptr, 4096, 4096, 1024);

  k_conv_silu<<<32768, 256, 0, stream>>>(xz, conv_w, conv_b, xbt);

  // bc = xbt @ W_x[:, :32]
  k_bc_mfma<<<dim3(4096 / 128, KS), 256, 0, stream>>>(xbt, WxBCT, bcp);
  k_bc_red<<<131072 / 256, 256, 0, stream>>>(bcp, bc);

  // dtin = xbt @ W_x[:,32:]  (bf16 out)
  gemm8p<128, 1><<<256, 512, 0, stream>>>(xbt, WxT, dtin, nullptr, 4096, 2048, 2048);

  // dlt = softplus(dtin @ W_dt + b_dt)  (f32 out)
  gemm8p<128, 2><<<256, 512, 0, stream>>>(dtin, WdtT, dlt, b_dt, 4096, 2048, 2048);

  // chunked scan
  k_scan_p1<<<dim3(DINNER / 256, NC, 2), 256, 0, stream>>>(dlt, xbt, bc, A_log, Pc, Qc);
  k_scan_p2<<<256, 256, 0, stream>>>(Pc, Qc, Hs);
  k_scan_p3<<<dim3(DINNER / 256, NC, 2), 256, 0, stream>>>(
      dlt, xbt, bc, xz, A_log, Dskip, Hs, yg);

  // out = yg @ W_out, transposed store + residual
  gemm_bf16<3><<<dim3(1024 / 128, 4096 / 128), 256, 0, stream>>>(
      yg, WoutT, out, nullptr, x, 4096, 1024, 2048);
}